// Round 1
// baseline (411.845 us; speedup 1.0000x reference)
//
#include <hip/hip_runtime.h>

// Problem constants
#define BATCH 4
#define CIN   256
#define COUT  256
#define HGT   64
#define WID   64
#define HW    4096      // HGT*WID
#define DGRP  4         // deformable groups
#define CG    64        // channels per deformable group
#define KK    9         // 3x3 taps
#define NCH   36        // DGRP*KK
#define KTOT  2304      // DGRP*KK*CG
#define GNUM  32        // GroupNorm groups
#define GSZ   8         // channels per GN group
#define GN_N  32768.0f  // elements per GN group = GSZ*HW

// ws layout (float offsets)
#define OFF_COEFF 0
#define SZ_COEFF  (BATCH*HW*NCH*4)          // 2,359,296 floats (float4 per position)
#define OFF_WT    (OFF_COEFF + SZ_COEFF)    // wT[2304][256]
#define SZ_WT     (KTOT*COUT)               // 589,824
#define OFF_Y     (OFF_WT + SZ_WT)
#define SZ_Y      (BATCH*COUT*HW)           // 4,194,304
#define OFF_GSUM  (OFF_Y + SZ_Y)
#define OFF_GSQ   (OFF_GSUM + 128)
#define OFF_MEAN  (OFF_GSQ + 128)
#define OFF_RSTD  (OFF_MEAN + 128)
// total ~7.15M floats = ~28.6 MB of ws

// ---------------------------------------------------------------------------
// Kernel 1: bilinear coefficients per (b, pix, dg, kk).
// coeff[(b*HW+pix)*NCH + dgkk] = float4{ y0(int bits), x0(int bits), wy1, wx1 }
__global__ void offs_kernel(const float* __restrict__ shp,
                            const float* __restrict__ wo,
                            float4* __restrict__ coeff) {
    int tid = blockIdx.x * 256 + threadIdx.x;
    if (tid >= BATCH * HW * NCH) return;
    int dgkk = tid % NCH;
    int pix  = (tid / NCH) % HW;
    int b    = tid / (NCH * HW);
    int kk   = dgkk % KK;

    float s0 = shp[(b*4 + 0)*HW + pix];
    float s1 = shp[(b*4 + 1)*HW + pix];
    float s2 = shp[(b*4 + 2)*HW + pix];
    float s3 = shp[(b*4 + 3)*HW + pix];
    const float* w0 = wo + (dgkk * 2) * 4;     // dy row
    const float* w1 = w0 + 4;                  // dx row
    float offy = s0*w0[0] + s1*w0[1] + s2*w0[2] + s3*w0[3];
    float offx = s0*w1[0] + s1*w1[1] + s2*w1[2] + s3*w1[3];

    int h = pix >> 6, w = pix & 63;
    float py = (float)(h + kk/3 - 1) + offy;
    float px = (float)(w + kk%3 - 1) + offx;
    float y0f = floorf(py), x0f = floorf(px);
    float4 o;
    o.x = __int_as_float((int)y0f);
    o.y = __int_as_float((int)x0f);
    o.z = py - y0f;
    o.w = px - x0f;
    coeff[tid] = o;
}

// ---------------------------------------------------------------------------
// Kernel 2: transpose deform weight to wT[k][o], k = (dg*9+kk)*64 + c
__global__ void wt_kernel(const float* __restrict__ wd, float* __restrict__ wT) {
    int tid = blockIdx.x * 256 + threadIdx.x;
    if (tid >= KTOT * COUT) return;
    int o = tid & 255;
    int k = tid >> 8;
    int c    = k & 63;
    int dgkk = k >> 6;
    int dg = dgkk / 9, kk = dgkk % 9;
    wT[tid] = wd[o * KTOT + (dg*CG + c) * 9 + kk];
}

// ---------------------------------------------------------------------------
// Kernel 3: fused bilinear-sample + implicit GEMM + GN partial sums.
// Grid: 512 blocks (b in [0,4), 128 pixel-tiles of 32). Block: 256 threads.
// Per chunk (dg,kk): stage S[c=64][pix=32] in LDS, then each thread does
// 4 out-ch x 8 pixels register tile over k=0..63.
__launch_bounds__(256, 4)
__global__ void main_kernel(const float* __restrict__ x,
                            const float4* __restrict__ coeff,
                            const float* __restrict__ wT,
                            float* __restrict__ y,
                            float* __restrict__ gsum,
                            float* __restrict__ gsq) {
    __shared__ float4 C4[NCH * 32];     // [dgkk][pix]
    __shared__ float  S[64 * 32];       // [c][pix]
    __shared__ float  lsum[GNUM], lsq[GNUM];

    const int tid  = threadIdx.x;
    const int b    = blockIdx.x >> 7;
    const int pix0 = (blockIdx.x & 127) << 5;

    // stage coefficients for this pixel tile (transposed to [dgkk][pix])
    const float4* cg = coeff + (b * HW + pix0) * NCH;
    for (int i = tid; i < 32 * NCH; i += 256) {
        int p = i / NCH, d = i % NCH;
        C4[d * 32 + p] = cg[i];
    }
    if (tid < GNUM) { lsum[tid] = 0.f; lsq[tid] = 0.f; }

    float acc[4][8];
#pragma unroll
    for (int i = 0; i < 4; ++i)
#pragma unroll
        for (int j = 0; j < 8; ++j) acc[i][j] = 0.f;

    const int o_grp = tid & 63;   // 4 out-channels: o_grp*4 ..
    const int p_grp = tid >> 6;   // 8 pixels:      p_grp*8 ..
    const int pixs  = tid & 31;   // sampling-phase pixel
    const int cslot = tid >> 5;   // sampling-phase channel slot (8 ch each)

    for (int ch = 0; ch < NCH; ++ch) {
        __syncthreads();   // protect S (prev GEMM reads) + first-iter LDS init
        // ---- sampling phase ----
        {
            float4 cf = C4[ch * 32 + pixs];
            int y0 = __float_as_int(cf.x), x0 = __float_as_int(cf.y);
            float wy1 = cf.z, wx1 = cf.w;
            float wy0 = 1.f - wy1, wx0 = 1.f - wx1;
            int y1 = y0 + 1, x1 = x0 + 1;
            bool vy0 = (unsigned)y0 < 64u, vy1 = (unsigned)y1 < 64u;
            bool vx0 = (unsigned)x0 < 64u, vx1 = (unsigned)x1 < 64u;
            int cy0 = min(max(y0, 0), 63), cy1 = min(max(y1, 0), 63);
            int cx0 = min(max(x0, 0), 63), cx1 = min(max(x1, 0), 63);
            float w00 = (vy0 && vx0) ? wy0 * wx0 : 0.f;
            float w01 = (vy0 && vx1) ? wy0 * wx1 : 0.f;
            float w10 = (vy1 && vx0) ? wy1 * wx0 : 0.f;
            float w11 = (vy1 && vx1) ? wy1 * wx1 : 0.f;
            int i00 = cy0 * 64 + cx0, i01 = cy0 * 64 + cx1;
            int i10 = cy1 * 64 + cx0, i11 = cy1 * 64 + cx1;
            int dg = ch / 9;
            const float* xp = x + (size_t)((b * DGRP + dg) * CG + cslot * 8) * HW;
#pragma unroll
            for (int j = 0; j < 8; ++j) {
                float v = w00 * xp[i00] + w01 * xp[i01]
                        + w10 * xp[i10] + w11 * xp[i11];
                S[(cslot * 8 + j) * 32 + pixs] = v;
                xp += HW;
            }
        }
        __syncthreads();
        // ---- GEMM phase: k = 0..63 over this chunk ----
        const float* wp = wT + (size_t)ch * 64 * 256 + o_grp * 4;
        const float4* S4 = (const float4*)S;
#pragma unroll 4
        for (int k = 0; k < 64; ++k) {
            float4 wv = *(const float4*)(wp + k * 256);
            float4 sa = S4[k * 8 + p_grp * 2];
            float4 sb = S4[k * 8 + p_grp * 2 + 1];
            float wr[4] = {wv.x, wv.y, wv.z, wv.w};
            float sr[8] = {sa.x, sa.y, sa.z, sa.w, sb.x, sb.y, sb.z, sb.w};
#pragma unroll
            for (int oi = 0; oi < 4; ++oi)
#pragma unroll
                for (int pj = 0; pj < 8; ++pj)
                    acc[oi][pj] += wr[oi] * sr[pj];
        }
    }

    // ---- epilogue: write y, accumulate GN stats ----
    float s_ = 0.f, q_ = 0.f;
#pragma unroll
    for (int oi = 0; oi < 4; ++oi) {
#pragma unroll
        for (int pj = 0; pj < 8; ++pj) {
            float v = acc[oi][pj];
            s_ += v; q_ += v * v;
        }
        float* yr = y + (size_t)(b * COUT + o_grp * 4 + oi) * HW + pix0 + p_grp * 8;
        float4 v0 = {acc[oi][0], acc[oi][1], acc[oi][2], acc[oi][3]};
        float4 v1 = {acc[oi][4], acc[oi][5], acc[oi][6], acc[oi][7]};
        ((float4*)yr)[0] = v0;
        ((float4*)yr)[1] = v1;
    }
    atomicAdd(&lsum[o_grp >> 1], s_);   // gn = (o_grp*4)/8
    atomicAdd(&lsq [o_grp >> 1], q_);
    __syncthreads();
    if (tid < GNUM) {
        atomicAdd(&gsum[b * GNUM + tid], lsum[tid]);
        atomicAdd(&gsq [b * GNUM + tid], lsq [tid]);
    }
}

// ---------------------------------------------------------------------------
// Kernel 4: finalize GN statistics (128 groups)
__global__ void stats_kernel(const float* __restrict__ gsum,
                             const float* __restrict__ gsq,
                             float* __restrict__ mean,
                             float* __restrict__ rstd) {
    int t = threadIdx.x;
    if (t < BATCH * GNUM) {
        float m = gsum[t] * (1.f / GN_N);
        float v = gsq[t] * (1.f / GN_N) - m * m;
        mean[t] = m;
        rstd[t] = rsqrtf(v + 1e-5f);
    }
}

// ---------------------------------------------------------------------------
// Kernel 5: apply GN affine + ReLU (float4, memory-bound)
__global__ void apply_kernel(const float* __restrict__ y,
                             const float* __restrict__ mean,
                             const float* __restrict__ rstd,
                             const float* __restrict__ gamma,
                             const float* __restrict__ beta,
                             float* __restrict__ out) {
    int i = blockIdx.x * 256 + threadIdx.x;        // float4 index
    if (i >= (BATCH * COUT * HW) / 4) return;
    float4 v = ((const float4*)y)[i];
    int idx = i * 4;
    int b = idx >> 20;            // / (COUT*HW)
    int c = (idx >> 12) & 255;    // / HW % COUT
    int gi = b * GNUM + (c >> 3);
    float r = rstd[gi];
    float g = gamma[c] * r;
    float be = beta[c] - mean[gi] * g;
    float4 o;
    o.x = fmaxf(v.x * g + be, 0.f);
    o.y = fmaxf(v.y * g + be, 0.f);
    o.z = fmaxf(v.z * g + be, 0.f);
    o.w = fmaxf(v.w * g + be, 0.f);
    ((float4*)out)[i] = o;
}

// ---------------------------------------------------------------------------
extern "C" void kernel_launch(void* const* d_in, const int* in_sizes, int n_in,
                              void* d_out, int out_size, void* d_ws, size_t ws_size,
                              hipStream_t stream) {
    const float* x     = (const float*)d_in[0];
    const float* shp   = (const float*)d_in[1];
    const float* wo    = (const float*)d_in[2];
    const float* wd    = (const float*)d_in[3];
    const float* gamma = (const float*)d_in[4];
    const float* beta  = (const float*)d_in[5];
    float* out = (float*)d_out;
    float* ws  = (float*)d_ws;

    float4* coeff = (float4*)(ws + OFF_COEFF);
    float*  wT    = ws + OFF_WT;
    float*  y     = ws + OFF_Y;
    float*  gsum  = ws + OFF_GSUM;
    float*  gsq   = ws + OFF_GSQ;
    float*  mean  = ws + OFF_MEAN;
    float*  rstd  = ws + OFF_RSTD;

    // zero the GN accumulators (ws is re-poisoned before every timed call)
    hipMemsetAsync(gsum, 0, 256 * sizeof(float), stream);

    offs_kernel<<<dim3((BATCH*HW*NCH + 255) / 256), dim3(256), 0, stream>>>(shp, wo, coeff);
    wt_kernel<<<dim3((KTOT*COUT + 255) / 256), dim3(256), 0, stream>>>(wd, wT);
    main_kernel<<<dim3(512), dim3(256), 0, stream>>>(x, coeff, wT, y, gsum, gsq);
    stats_kernel<<<dim3(1), dim3(128), 0, stream>>>(gsum, gsq, mean, rstd);
    apply_kernel<<<dim3((BATCH*COUT*HW/4 + 255) / 256), dim3(256), 0, stream>>>(
        y, mean, rstd, gamma, beta, out);
}

// Round 4
// 221.424 us; speedup vs baseline: 1.8600x; 1.8600x over previous
//
#include <hip/hip_runtime.h>

// Problem constants
#define BATCH 4
#define COUT  256
#define HW    4096      // 64*64
#define DGRP  4         // deformable groups
#define CG    64        // channels per deformable group
#define KK    9         // 3x3 taps
#define NCH   36        // DGRP*KK chunks of 64 input-channels
#define KTOT  2304      // DGRP*KK*CG
#define NKSTEP 72       // KTOT/32 mfma K-steps
#define GNUM  32        // GroupNorm groups
#define GN_N  32768.0f  // elements per GN group
#define TP    32        // pixels per tile (BM)

// ws layout (float offsets)
#define OFF_COEFF 0
#define SZ_COEFF  (BATCH*NCH*HW*4)          // [b][dgkk][pix] float4
#define OFF_WB    (OFF_COEFF + SZ_COEFF)    // bf16 wB[72][256][32] (as ushort)
#define SZ_WB     (KTOT*COUT/2)             // 294,912 floats
#define OFF_Y     (OFF_WB + SZ_WB)
#define SZ_Y      (BATCH*COUT*HW)
#define OFF_GSUM  (OFF_Y + SZ_Y)
#define OFF_GSQ   (OFF_GSUM + 128)
#define OFF_MEAN  (OFF_GSQ + 128)
#define OFF_RSTD  (OFF_MEAN + 128)

typedef __attribute__((ext_vector_type(8))) short short8;
typedef __attribute__((ext_vector_type(4))) float f32x4;

__device__ __forceinline__ ushort f2bf(float f) {
    unsigned u = __float_as_uint(f);
    unsigned r = (u + 0x7FFFu + ((u >> 16) & 1u)) >> 16;   // RNE
    return (ushort)r;
}

// ---------------------------------------------------------------------------
// Kernel 1: bilinear coefficients, layout [b][dgkk][pix] (coalesced in pix).
// coeff = float4{ y0(int bits), x0(int bits), wy1, wx1 }
__global__ void offs_kernel(const float* __restrict__ shp,
                            const float* __restrict__ wo,
                            float4* __restrict__ coeff) {
    int tid = blockIdx.x * 256 + threadIdx.x;
    if (tid >= BATCH * NCH * HW) return;
    int pix  = tid & (HW - 1);
    int rest = tid >> 12;
    int dgkk = rest % NCH;
    int b    = rest / NCH;
    int kk   = dgkk % KK;

    float s0 = shp[(b*4 + 0)*HW + pix];
    float s1 = shp[(b*4 + 1)*HW + pix];
    float s2 = shp[(b*4 + 2)*HW + pix];
    float s3 = shp[(b*4 + 3)*HW + pix];
    const float* w0 = wo + (dgkk * 2) * 4;     // dy row
    const float* w1 = w0 + 4;                  // dx row
    float offy = s0*w0[0] + s1*w0[1] + s2*w0[2] + s3*w0[3];
    float offx = s0*w1[0] + s1*w1[1] + s2*w1[2] + s3*w1[3];

    int h = pix >> 6, w = pix & 63;
    float py = (float)(h + kk/3 - 1) + offy;
    float px = (float)(w + kk%3 - 1) + offx;
    float y0f = floorf(py), x0f = floorf(px);
    float4 o;
    o.x = __int_as_float((int)y0f);
    o.y = __int_as_float((int)x0f);
    o.z = py - y0f;
    o.w = px - x0f;
    coeff[tid] = o;   // tid == (b*NCH+dgkk)*HW + pix
}

// ---------------------------------------------------------------------------
// Kernel 2: pack deform weight to bf16 wB[kstep][out][k32],
// k = kstep*32 + k32 = (dg*9+kk)*64 + c  (c = channel within deform group)
__global__ void wb_kernel(const float* __restrict__ wd, ushort* __restrict__ wB) {
    int tid = blockIdx.x * 256 + threadIdx.x;
    if (tid >= NKSTEP * COUT * 32) return;
    int k32   = tid & 31;
    int out   = (tid >> 5) & 255;
    int kstep = tid >> 13;
    int k    = kstep * 32 + k32;
    int dgkk = k >> 6;
    int c    = k & 63;
    int dg = dgkk / KK, kk = dgkk % KK;
    wB[tid] = f2bf(wd[out * KTOT + (dg * CG + c) * KK + kk]);
}

// ---------------------------------------------------------------------------
// Kernel 3: fused bilinear-sample + bf16-MFMA implicit GEMM + GN partials.
// Grid: 512 blocks (b * 128 pixel-tiles of 32). Block: 256 threads (4 waves).
// Output tile 32 pix x 256 out; wave w owns out range w*64..w*64+63.
// A (S) = sampled values bf16 in swizzled LDS [pix][c]; B = wB from global
// (L2-resident). MFMA 16x16x32: A m=lane&15, k=(lane>>4)*8+j; B n=lane&15,
// same k; D n=lane&15, m=(lane>>4)*4+reg (verified layout).
__launch_bounds__(256, 2)
__global__ void main_kernel(const float* __restrict__ x,
                            const float4* __restrict__ coeff,
                            const ushort* __restrict__ wB,
                            float* __restrict__ y,
                            float* __restrict__ gsum,
                            float* __restrict__ gsq) {
    __shared__ ushort Sm[2][TP * 64];      // [pix][c] bf16, XOR-swizzled 16B slots
    __shared__ float lsum[GNUM], lsq[GNUM];

    const int tid   = threadIdx.x;
    const int lane  = tid & 63;
    const int wv    = tid >> 6;                 // wave id 0..3
    const int b     = blockIdx.x >> 7;          // 128 tiles per batch
    const int pix0  = (blockIdx.x & 127) << 5;
    const int pixs  = tid & 31;                 // sampling-phase pixel
    const int cslot = tid >> 5;                 // sampling-phase 8-channel slot

    if (tid < GNUM) { lsum[tid] = 0.f; lsq[tid] = 0.f; }

    f32x4 acc[4][2];                            // [n-tile][m-tile]
#pragma unroll
    for (int i = 0; i < 4; ++i)
#pragma unroll
        for (int j = 0; j < 2; ++j) acc[i][j] = (f32x4)0.f;

    float lv[4][8];   // [tap][ch j] raw gathers for next chunk
    float wgt[4];     // bilinear weights for next chunk

    auto sample_load = [&](int ch) {
        float4 cf = coeff[(size_t)(b * NCH + ch) * HW + pix0 + pixs];
        int y0 = __float_as_int(cf.x), x0 = __float_as_int(cf.y);
        float wy1 = cf.z, wx1 = cf.w;
        float wy0 = 1.f - wy1, wx0 = 1.f - wx1;
        int y1 = y0 + 1, x1 = x0 + 1;
        bool vy0 = (unsigned)y0 < 64u, vy1 = (unsigned)y1 < 64u;
        bool vx0 = (unsigned)x0 < 64u, vx1 = (unsigned)x1 < 64u;
        int cy0 = min(max(y0, 0), 63), cy1 = min(max(y1, 0), 63);
        int cx0 = min(max(x0, 0), 63), cx1 = min(max(x1, 0), 63);
        wgt[0] = (vy0 && vx0) ? wy0 * wx0 : 0.f;
        wgt[1] = (vy0 && vx1) ? wy0 * wx1 : 0.f;
        wgt[2] = (vy1 && vx0) ? wy1 * wx0 : 0.f;
        wgt[3] = (vy1 && vx1) ? wy1 * wx1 : 0.f;
        int i00 = cy0 * 64 + cx0, i01 = cy0 * 64 + cx1;
        int i10 = cy1 * 64 + cx0, i11 = cy1 * 64 + cx1;
        int dg = ch / KK;
        const float* xp = x + (size_t)((b * DGRP + dg) * CG + cslot * 8) * HW;
#pragma unroll
        for (int j = 0; j < 8; ++j) {
            lv[0][j] = xp[i00];
            lv[1][j] = xp[i01];
            lv[2][j] = xp[i10];
            lv[3][j] = xp[i11];
            xp += HW;
        }
    };
    auto sample_store = [&](int buf) {
        short8 frag;
#pragma unroll
        for (int j = 0; j < 8; ++j) {
            float v = wgt[0]*lv[0][j] + wgt[1]*lv[1][j]
                    + wgt[2]*lv[2][j] + wgt[3]*lv[3][j];
            frag[j] = (short)f2bf(v);
        }
        int swslot = cslot ^ (pixs & 7);        // T2 XOR swizzle, 16B slots
        *reinterpret_cast<short8*>(&Sm[buf][pixs * 64 + swslot * 8]) = frag;
    };

    // prologue: chunk 0
    sample_load(0);
    sample_store(0);
    __syncthreads();

    for (int ch = 0; ch < NCH; ++ch) {
        if (ch + 1 < NCH) sample_load(ch + 1);   // gathers in flight during GEMM

        const ushort* Sb = Sm[ch & 1];
#pragma unroll
        for (int ss = 0; ss < 2; ++ss) {
            const int kstep = ch * 2 + ss;
            // A-frags: pix = mt*16 + (lane&15), k8-block = lane>>4
            short8 afrag[2];
#pragma unroll
            for (int mt = 0; mt < 2; ++mt) {
                int pix  = mt * 16 + (lane & 15);
                int slot = (ss * 4 + (lane >> 4)) ^ (pix & 7);
                afrag[mt] = *reinterpret_cast<const short8*>(&Sb[pix * 64 + slot * 8]);
            }
#pragma unroll
            for (int nt = 0; nt < 4; ++nt) {
                int out = wv * 64 + nt * 16 + (lane & 15);
                const short8* bp = reinterpret_cast<const short8*>(
                    wB + ((size_t)(kstep * 256 + out) * 32 + (lane >> 4) * 8));
                short8 bfrag = *bp;
#pragma unroll
                for (int mt = 0; mt < 2; ++mt)
                    acc[nt][mt] = __builtin_amdgcn_mfma_f32_16x16x32_bf16(
                        afrag[mt], bfrag, acc[nt][mt], 0, 0, 0);
            }
        }

        if (ch + 1 < NCH) sample_store((ch + 1) & 1);
        __syncthreads();
    }

    // ---- epilogue: write y, accumulate GN stats ----
#pragma unroll
    for (int nt = 0; nt < 4; ++nt) {
        int out = wv * 64 + nt * 16 + (lane & 15);
        float s_ = 0.f, q_ = 0.f;
#pragma unroll
        for (int mt = 0; mt < 2; ++mt) {
            float4 st;
            st.x = acc[nt][mt][0]; st.y = acc[nt][mt][1];
            st.z = acc[nt][mt][2]; st.w = acc[nt][mt][3];
            s_ += st.x + st.y + st.z + st.w;
            q_ += st.x*st.x + st.y*st.y + st.z*st.z + st.w*st.w;
            float* yr = y + (size_t)(b * COUT + out) * HW
                          + pix0 + mt * 16 + (lane >> 4) * 4;
            *reinterpret_cast<float4*>(yr) = st;
        }
        atomicAdd(&lsum[out >> 3], s_);
        atomicAdd(&lsq [out >> 3], q_);
    }
    __syncthreads();
    if (tid < GNUM) {
        atomicAdd(&gsum[b * GNUM + tid], lsum[tid]);
        atomicAdd(&gsq [b * GNUM + tid], lsq [tid]);
    }
}

// ---------------------------------------------------------------------------
// Kernel 4: finalize GN statistics (128 groups)
__global__ void stats_kernel(const float* __restrict__ gsum,
                             const float* __restrict__ gsq,
                             float* __restrict__ mean,
                             float* __restrict__ rstd) {
    int t = threadIdx.x;
    if (t < BATCH * GNUM) {
        float m = gsum[t] * (1.f / GN_N);
        float v = gsq[t] * (1.f / GN_N) - m * m;
        mean[t] = m;
        rstd[t] = rsqrtf(v + 1e-5f);
    }
}

// ---------------------------------------------------------------------------
// Kernel 5: apply GN affine + ReLU (float4, memory-bound)
__global__ void apply_kernel(const float* __restrict__ y,
                             const float* __restrict__ mean,
                             const float* __restrict__ rstd,
                             const float* __restrict__ gamma,
                             const float* __restrict__ beta,
                             float* __restrict__ out) {
    int i = blockIdx.x * 256 + threadIdx.x;        // float4 index
    if (i >= (BATCH * COUT * HW) / 4) return;
    float4 v = ((const float4*)y)[i];
    int idx = i * 4;
    int b = idx >> 20;
    int c = (idx >> 12) & 255;
    int gi = b * GNUM + (c >> 3);
    float r = rstd[gi];
    float g = gamma[c] * r;
    float be = beta[c] - mean[gi] * g;
    float4 o;
    o.x = fmaxf(v.x * g + be, 0.f);
    o.y = fmaxf(v.y * g + be, 0.f);
    o.z = fmaxf(v.z * g + be, 0.f);
    o.w = fmaxf(v.w * g + be, 0.f);
    ((float4*)out)[i] = o;
}

// ---------------------------------------------------------------------------
extern "C" void kernel_launch(void* const* d_in, const int* in_sizes, int n_in,
                              void* d_out, int out_size, void* d_ws, size_t ws_size,
                              hipStream_t stream) {
    const float* x     = (const float*)d_in[0];
    const float* shp   = (const float*)d_in[1];
    const float* wo    = (const float*)d_in[2];
    const float* wd    = (const float*)d_in[3];
    const float* gamma = (const float*)d_in[4];
    const float* beta  = (const float*)d_in[5];
    float* out = (float*)d_out;
    float* ws  = (float*)d_ws;

    float4* coeff = (float4*)(ws + OFF_COEFF);
    ushort* wB    = (ushort*)(ws + OFF_WB);
    float*  y     = ws + OFF_Y;
    float*  gsum  = ws + OFF_GSUM;
    float*  gsq   = ws + OFF_GSQ;
    float*  mean  = ws + OFF_MEAN;
    float*  rstd  = ws + OFF_RSTD;

    hipMemsetAsync(gsum, 0, 256 * sizeof(float), stream);

    offs_kernel<<<dim3((BATCH*NCH*HW + 255) / 256), dim3(256), 0, stream>>>(shp, wo, coeff);
    wb_kernel<<<dim3((NKSTEP*COUT*32 + 255) / 256), dim3(256), 0, stream>>>(wd, wB);
    main_kernel<<<dim3(512), dim3(256), 0, stream>>>(x, coeff, wB, y, gsum, gsq);
    stats_kernel<<<dim3(1), dim3(128), 0, stream>>>(gsum, gsq, mean, rstd);
    apply_kernel<<<dim3((BATCH*COUT*HW/4 + 255) / 256), dim3(256), 0, stream>>>(
        y, mean, rstd, gamma, beta, out);
}